// Round 1
// baseline (1093.491 us; speedup 1.0000x reference)
//
#include <hip/hip_runtime.h>
#include <hip/hip_bf16.h>
#include <stdint.h>

#define T_TOK 4096
#define DIMD  2048
#define NEXP  16
#define TOPK  4
#define NI    1024
#define NSH   2048

typedef __attribute__((ext_vector_type(8))) short short8;
typedef __attribute__((ext_vector_type(4))) float f32x4;

__device__ __forceinline__ unsigned short f2bf(float f) {
    union { float f; unsigned u; } v; v.f = f;
    return (unsigned short)((v.u + 0x7fffu + ((v.u >> 16) & 1u)) >> 16);
}

// ---------------- gate + routing ----------------
__global__ __launch_bounds__(64) void gate_kernel(const float* __restrict__ x,
                                                  const float* __restrict__ gw,
                                                  int* __restrict__ cnt,
                                                  int* __restrict__ list,
                                                  float* __restrict__ cw) {
    int t = blockIdx.x;
    int lane = threadIdx.x;
    float acc[NEXP];
#pragma unroll
    for (int e = 0; e < NEXP; ++e) acc[e] = 0.f;
    const float* xr = x + (size_t)t * DIMD;
    for (int d0 = 0; d0 < DIMD; d0 += 64) {
        int d = d0 + lane;
        float xv = xr[d];
        const f32x4* g = (const f32x4*)(gw + (size_t)d * NEXP);
#pragma unroll
        for (int q = 0; q < 4; ++q) {
            f32x4 gv = g[q];
#pragma unroll
            for (int j = 0; j < 4; ++j) acc[q * 4 + j] += xv * gv[j];
        }
    }
    // full-wave butterfly reduce -> every lane holds the total
#pragma unroll
    for (int e = 0; e < NEXP; ++e) {
        float v = acc[e];
#pragma unroll
        for (int off = 32; off; off >>= 1) v += __shfl_xor(v, off, 64);
        acc[e] = v;
    }
    // softmax over 16
    float m = acc[0];
#pragma unroll
    for (int e = 1; e < NEXP; ++e) m = fmaxf(m, acc[e]);
    float s = 0.f;
#pragma unroll
    for (int e = 0; e < NEXP; ++e) { acc[e] = expf(acc[e] - m); s += acc[e]; }
    float inv = 1.f / s;
#pragma unroll
    for (int e = 0; e < NEXP; ++e) acc[e] *= inv;

    if (lane == 0) {
        bool used[NEXP];
#pragma unroll
        for (int e = 0; e < NEXP; ++e) used[e] = false;
        for (int k = 0; k < TOPK; ++k) {
            int be = 0; float bv = -1.f;
            for (int e = 0; e < NEXP; ++e)
                if (!used[e] && acc[e] > bv) { bv = acc[e]; be = e; }
            used[be] = true;
            int r = atomicAdd(&cnt[be], 1);
            list[be * T_TOK + r] = t;
            cw[be * T_TOK + r] = bv;
        }
    }
}

__global__ void scan_kernel(const int* __restrict__ cnt, int* __restrict__ offs) {
    if (threadIdx.x == 0) {
        int o = 0;
        for (int e = 0; e < NEXP; ++e) { offs[e] = o; o += cnt[e]; }
        offs[NEXP] = o;
    }
}

// ---------------- x fp32 -> bf16 ----------------
__global__ __launch_bounds__(256) void cvt_kernel(const float* __restrict__ x,
                                                  unsigned short* __restrict__ xb) {
    int i = blockIdx.x * 256 + threadIdx.x;  // one i = 8 elements
    const f32x4* src = (const f32x4*)x;
    f32x4 a = src[i * 2 + 0];
    f32x4 b = src[i * 2 + 1];
    short8 o;
#pragma unroll
    for (int j = 0; j < 4; ++j) o[j] = (short)f2bf(a[j]);
#pragma unroll
    for (int j = 0; j < 4; ++j) o[4 + j] = (short)f2bf(b[j]);
    ((short8*)xb)[i] = o;
}

// ---------------- dual-B up-projection GEMM ----------------
// C1 = A@W1, C3 = A@W3, h = silu(C1)*C3 [*coef], bf16 out.
// Tile: BM=128, BN=64, BK=32. 256 thr = 4 waves (2x2), wave tile 64x32.
template <bool GATHER>
__global__ __launch_bounds__(256) void up_kernel(
    const unsigned short* __restrict__ xb, const float* __restrict__ w1b,
    const float* __restrict__ w3b, const int* __restrict__ cnt,
    const int* __restrict__ offs, const int* __restrict__ list,
    const float* __restrict__ cw, unsigned short* __restrict__ hout,
    int N, int K) {
    int e = blockIdx.z;
    int M = GATHER ? cnt[e] : T_TOK;
    int rb = blockIdx.y * 128;
    if (rb >= M) return;
    const float* w1 = w1b + (GATHER ? (size_t)e * K * N : 0);
    const float* w3 = w3b + (GATHER ? (size_t)e * K * N : 0);
    int n0 = blockIdx.x * 64;

    __shared__ unsigned short lA[128][40];
    __shared__ unsigned short lB1[64][40];
    __shared__ unsigned short lB3[64][40];

    int tid = threadIdx.x;
    int lane = tid & 63;
    int wid = tid >> 6;
    int wm = wid >> 1, wn = wid & 1;

    f32x4 acc1[4][2], acc3[4][2];
#pragma unroll
    for (int m = 0; m < 4; ++m)
#pragma unroll
        for (int n = 0; n < 2; ++n) {
            acc1[m][n] = (f32x4)0.f;
            acc3[m][n] = (f32x4)0.f;
        }

    // A staging map: 2 x (64 rows x 32 cols as 8-elem chunks)
    int ar = tid >> 2;
    int ac = (tid & 3) * 8;
    int tok[2];
#pragma unroll
    for (int h = 0; h < 2; ++h) {
        int gr = rb + ar + h * 64;
        if (GATHER) tok[h] = (gr < M) ? list[e * T_TOK + gr] : 0;
        else        tok[h] = gr;
    }
    // B staging map: 4n x 2k per thread
    int bn = (tid & 15) * 4;
    int bk = (tid >> 4) * 2;

    for (int k0 = 0; k0 < K; k0 += 32) {
#pragma unroll
        for (int h = 0; h < 2; ++h) {
            short8 v = *(const short8*)(xb + (size_t)tok[h] * K + k0 + ac);
            *(short8*)&lA[ar + h * 64][ac] = v;
        }
        {
            const float* s1 = w1 + (size_t)(k0 + bk) * N + n0 + bn;
            f32x4 r0 = *(const f32x4*)s1;
            f32x4 r1 = *(const f32x4*)(s1 + N);
#pragma unroll
            for (int j = 0; j < 4; ++j) {
                unsigned v = (unsigned)f2bf(r0[j]) | ((unsigned)f2bf(r1[j]) << 16);
                *(unsigned*)&lB1[bn + j][bk] = v;
            }
            const float* s3 = w3 + (size_t)(k0 + bk) * N + n0 + bn;
            f32x4 q0 = *(const f32x4*)s3;
            f32x4 q1 = *(const f32x4*)(s3 + N);
#pragma unroll
            for (int j = 0; j < 4; ++j) {
                unsigned v = (unsigned)f2bf(q0[j]) | ((unsigned)f2bf(q1[j]) << 16);
                *(unsigned*)&lB3[bn + j][bk] = v;
            }
        }
        __syncthreads();
        int fr = lane & 15, fk = (lane >> 4) * 8;
        short8 a[4];
#pragma unroll
        for (int m = 0; m < 4; ++m)
            a[m] = *(const short8*)&lA[wm * 64 + m * 16 + fr][fk];
#pragma unroll
        for (int n = 0; n < 2; ++n) {
            short8 b1 = *(const short8*)&lB1[wn * 32 + n * 16 + fr][fk];
            short8 b3 = *(const short8*)&lB3[wn * 32 + n * 16 + fr][fk];
#pragma unroll
            for (int m = 0; m < 4; ++m) {
                acc1[m][n] = __builtin_amdgcn_mfma_f32_16x16x32_bf16(a[m], b1, acc1[m][n], 0, 0, 0);
                acc3[m][n] = __builtin_amdgcn_mfma_f32_16x16x32_bf16(a[m], b3, acc3[m][n], 0, 0, 0);
            }
        }
        __syncthreads();
    }
    // epilogue
    int fr = lane & 15, fq = lane >> 4;
#pragma unroll
    for (int m = 0; m < 4; ++m)
#pragma unroll
        for (int n = 0; n < 2; ++n)
#pragma unroll
            for (int r = 0; r < 4; ++r) {
                int lr = wm * 64 + m * 16 + fq * 4 + r;
                int gr = rb + lr;
                if (gr < M) {
                    int col = n0 + wn * 32 + n * 16 + fr;
                    float c1 = acc1[m][n][r], c3 = acc3[m][n][r];
                    float h = c1 / (1.f + __expf(-c1)) * c3;
                    if constexpr (GATHER) {
                        h *= cw[e * T_TOK + gr];
                        hout[(size_t)(offs[e] + gr) * N + col] = f2bf(h);
                    } else {
                        hout[(size_t)gr * N + col] = f2bf(h);
                    }
                }
            }
}

// ---------------- down-projection GEMM ----------------
// C = A@W2 -> scatter atomicAdd into out (expert) or plain store (shared).
// Tile: BM=128, BN=128, BK=32. 4 waves (2x2), wave tile 64x64.
template <bool SCATTER>
__global__ __launch_bounds__(256) void down_kernel(
    const unsigned short* __restrict__ hin, const float* __restrict__ w2b,
    const int* __restrict__ cnt, const int* __restrict__ offs,
    const int* __restrict__ list, float* __restrict__ out, int K) {
    int e = blockIdx.z;
    int M = SCATTER ? cnt[e] : T_TOK;
    int rb = blockIdx.y * 128;
    if (rb >= M) return;
    const float* w2 = w2b + (SCATTER ? (size_t)e * K * DIMD : 0);
    int n0 = blockIdx.x * 128;
    int base = SCATTER ? offs[e] : 0;

    __shared__ unsigned short lA[128][40];
    __shared__ unsigned short lB[128][40];

    int tid = threadIdx.x;
    int lane = tid & 63;
    int wid = tid >> 6;
    int wm = wid >> 1, wn = wid & 1;

    f32x4 acc[4][4];
#pragma unroll
    for (int m = 0; m < 4; ++m)
#pragma unroll
        for (int n = 0; n < 4; ++n) acc[m][n] = (f32x4)0.f;

    int ar = tid >> 2;
    int ac = (tid & 3) * 8;
    size_t arow[2];
#pragma unroll
    for (int h = 0; h < 2; ++h) {
        int gr = rb + ar + h * 64;
        int rr = (gr < M) ? gr : (M - 1);
        arow[h] = (size_t)(base + rr) * K;
    }
    int bn = (tid & 31) * 4;
    int bk = (tid >> 5) * 4;

    for (int k0 = 0; k0 < K; k0 += 32) {
#pragma unroll
        for (int h = 0; h < 2; ++h) {
            short8 v = *(const short8*)(hin + arow[h] + k0 + ac);
            *(short8*)&lA[ar + h * 64][ac] = v;
        }
        {
            const float* s = w2 + (size_t)(k0 + bk) * DIMD + n0 + bn;
            f32x4 r0 = *(const f32x4*)s;
            f32x4 r1 = *(const f32x4*)(s + DIMD);
            f32x4 r2 = *(const f32x4*)(s + 2 * DIMD);
            f32x4 r3 = *(const f32x4*)(s + 3 * DIMD);
#pragma unroll
            for (int j = 0; j < 4; ++j) {
                unsigned long long v =
                    (unsigned long long)f2bf(r0[j]) |
                    ((unsigned long long)f2bf(r1[j]) << 16) |
                    ((unsigned long long)f2bf(r2[j]) << 32) |
                    ((unsigned long long)f2bf(r3[j]) << 48);
                *(unsigned long long*)&lB[bn + j][bk] = v;
            }
        }
        __syncthreads();
        int fr = lane & 15, fk = (lane >> 4) * 8;
        short8 a[4], b[4];
#pragma unroll
        for (int m = 0; m < 4; ++m)
            a[m] = *(const short8*)&lA[wm * 64 + m * 16 + fr][fk];
#pragma unroll
        for (int n = 0; n < 4; ++n)
            b[n] = *(const short8*)&lB[wn * 64 + n * 16 + fr][fk];
#pragma unroll
        for (int m = 0; m < 4; ++m)
#pragma unroll
            for (int n = 0; n < 4; ++n)
                acc[m][n] = __builtin_amdgcn_mfma_f32_16x16x32_bf16(a[m], b[n], acc[m][n], 0, 0, 0);
        __syncthreads();
    }
    int fr = lane & 15, fq = lane >> 4;
#pragma unroll
    for (int m = 0; m < 4; ++m)
#pragma unroll
        for (int n = 0; n < 4; ++n)
#pragma unroll
            for (int r = 0; r < 4; ++r) {
                int lr = wm * 64 + m * 16 + fq * 4 + r;
                int gr = rb + lr;
                if (gr < M) {
                    int col = n0 + wn * 64 + n * 16 + fr;
                    float v = acc[m][n][r];
                    if constexpr (SCATTER) {
                        int t = list[e * T_TOK + gr];
                        atomicAdd(&out[(size_t)t * DIMD + col], v);
                    } else {
                        out[(size_t)gr * DIMD + col] = v;
                    }
                }
            }
}

extern "C" void kernel_launch(void* const* d_in, const int* in_sizes, int n_in,
                              void* d_out, int out_size, void* d_ws, size_t ws_size,
                              hipStream_t stream) {
    const float* x   = (const float*)d_in[0];
    const float* gw  = (const float*)d_in[1];
    const float* w1  = (const float*)d_in[2];
    const float* w2  = (const float*)d_in[3];
    const float* w3  = (const float*)d_in[4];
    const float* ws1 = (const float*)d_in[5];
    const float* ws2 = (const float*)d_in[6];
    const float* ws3 = (const float*)d_in[7];
    float* out = (float*)d_out;

    char* p = (char*)d_ws;
    unsigned short* xb = (unsigned short*)p;   p += (size_t)T_TOK * DIMD * 2;   // 16.8 MB
    unsigned short* hs = (unsigned short*)p;   p += (size_t)T_TOK * NSH * 2;    // 16.8 MB
    unsigned short* hbuf = (unsigned short*)p; p += (size_t)T_TOK * TOPK * NI * 2; // 33.6 MB
    float* cw = (float*)p;                     p += (size_t)NEXP * T_TOK * 4;   // 256 KB
    int* list = (int*)p;                       p += (size_t)NEXP * T_TOK * 4;   // 256 KB
    int* cnt = (int*)p;                        p += 256;
    int* offs = (int*)p;                       p += 256;
    if ((size_t)(p - (char*)d_ws) > ws_size) return;  // ws too small -> visible failure

    hipMemsetAsync(cnt, 0, 64, stream);
    gate_kernel<<<T_TOK, 64, 0, stream>>>(x, gw, cnt, list, cw);
    scan_kernel<<<1, 64, 0, stream>>>(cnt, offs);
    cvt_kernel<<<(T_TOK * DIMD / 8) / 256, 256, 0, stream>>>(x, xb);

    // shared expert: h_s = silu(x@ws1)*(x@ws3)
    dim3 gsu(NSH / 64, T_TOK / 128, 1);
    up_kernel<false><<<gsu, 256, 0, stream>>>(xb, ws1, ws3, nullptr, nullptr,
                                              nullptr, nullptr, hs, NSH, DIMD);
    // z = h_s @ ws2  (plain store -> initializes out)
    dim3 gsd(DIMD / 128, T_TOK / 128, 1);
    down_kernel<false><<<gsd, 256, 0, stream>>>(hs, ws2, nullptr, nullptr,
                                                nullptr, out, NSH);
    // routed experts: gathered rows, coef folded into h
    dim3 geu(NI / 64, T_TOK / 128, NEXP);
    up_kernel<true><<<geu, 256, 0, stream>>>(xb, w1, w3, cnt, offs, list, cw,
                                             hbuf, NI, DIMD);
    dim3 ged(DIMD / 128, T_TOK / 128, NEXP);
    down_kernel<true><<<ged, 256, 0, stream>>>(hbuf, w2, cnt, offs, list, out, NI);
}

// Round 2
// 1020.030 us; speedup vs baseline: 1.0720x; 1.0720x over previous
//
#include <hip/hip_runtime.h>
#include <hip/hip_bf16.h>
#include <stdint.h>

#define T_TOK 4096
#define DIMD  2048
#define NEXP  16
#define TOPK  4
#define NI    1024
#define NSH   2048

typedef __attribute__((ext_vector_type(8))) short short8;
typedef __attribute__((ext_vector_type(4))) float f32x4;
typedef __attribute__((ext_vector_type(4))) unsigned short u16x4;

__device__ __forceinline__ unsigned short f2bf(float f) {
    union { float f; unsigned u; } v; v.f = f;
    return (unsigned short)((v.u + 0x7fffu + ((v.u >> 16) & 1u)) >> 16);
}

__device__ __forceinline__ void gload16(const void* g, void* l) {
    __builtin_amdgcn_global_load_lds(
        (const __attribute__((address_space(1))) void*)g,
        (__attribute__((address_space(3))) void*)l, 16, 0, 0);
}

// ---------------- gate + routing ----------------
__global__ __launch_bounds__(64) void gate_kernel(const float* __restrict__ x,
                                                  const float* __restrict__ gw,
                                                  int* __restrict__ cnt,
                                                  int* __restrict__ list,
                                                  float* __restrict__ cw) {
    int t = blockIdx.x;
    int lane = threadIdx.x;
    float acc[NEXP];
#pragma unroll
    for (int e = 0; e < NEXP; ++e) acc[e] = 0.f;
    const float* xr = x + (size_t)t * DIMD;
    for (int d0 = 0; d0 < DIMD; d0 += 64) {
        int d = d0 + lane;
        float xv = xr[d];
        const f32x4* g = (const f32x4*)(gw + (size_t)d * NEXP);
#pragma unroll
        for (int q = 0; q < 4; ++q) {
            f32x4 gv = g[q];
#pragma unroll
            for (int j = 0; j < 4; ++j) acc[q * 4 + j] += xv * gv[j];
        }
    }
#pragma unroll
    for (int e = 0; e < NEXP; ++e) {
        float v = acc[e];
#pragma unroll
        for (int off = 32; off; off >>= 1) v += __shfl_xor(v, off, 64);
        acc[e] = v;
    }
    float m = acc[0];
#pragma unroll
    for (int e = 1; e < NEXP; ++e) m = fmaxf(m, acc[e]);
    float s = 0.f;
#pragma unroll
    for (int e = 0; e < NEXP; ++e) { acc[e] = expf(acc[e] - m); s += acc[e]; }
    float inv = 1.f / s;
#pragma unroll
    for (int e = 0; e < NEXP; ++e) acc[e] *= inv;

    if (lane == 0) {
        bool used[NEXP];
#pragma unroll
        for (int e = 0; e < NEXP; ++e) used[e] = false;
        for (int k = 0; k < TOPK; ++k) {
            int be = 0; float bv = -1.f;
            for (int e = 0; e < NEXP; ++e)
                if (!used[e] && acc[e] > bv) { bv = acc[e]; be = e; }
            used[be] = true;
            int r = atomicAdd(&cnt[be], 1);
            list[be * T_TOK + r] = t;
            cw[be * T_TOK + r] = bv;
        }
    }
}

__global__ void scan_kernel(const int* __restrict__ cnt, int* __restrict__ offs) {
    if (threadIdx.x == 0) {
        int o = 0;
        for (int e = 0; e < NEXP; ++e) { offs[e] = o; o += cnt[e]; }
        offs[NEXP] = o;
    }
}

// ---------------- x fp32 -> bf16 ----------------
__global__ __launch_bounds__(256) void cvt_kernel(const float* __restrict__ x,
                                                  unsigned short* __restrict__ xb) {
    int i = blockIdx.x * 256 + threadIdx.x;
    const f32x4* src = (const f32x4*)x;
    f32x4 a = src[i * 2 + 0];
    f32x4 b = src[i * 2 + 1];
    short8 o;
#pragma unroll
    for (int j = 0; j < 4; ++j) o[j] = (short)f2bf(a[j]);
#pragma unroll
    for (int j = 0; j < 4; ++j) o[4 + j] = (short)f2bf(b[j]);
    ((short8*)xb)[i] = o;
}

// ---------------- weight transpose + convert ----------------
// src fp32 [K][N] -> dst bf16 [N'][K].
// MODE 0: row r = n. MODE 1: r = (n>>4)*32 + (n&15) (w1 half).
// MODE 2: r = (n>>4)*32 + 16 + (n&15) (w3 half).
template <int MODE>
__global__ __launch_bounds__(256) void tq_kernel(const float* __restrict__ src,
                                                 unsigned short* __restrict__ dst,
                                                 int K, int N, size_t dstStrideE) {
    int e = blockIdx.z;
    src += (size_t)e * K * N;
    dst += (size_t)e * dstStrideE;
    __shared__ unsigned short tile[32][36];
    int t = threadIdx.x;
    int k0 = blockIdx.y * 32, n0 = blockIdx.x * 32;
    {
        int row = t >> 3, c4 = (t & 7) * 4;
        f32x4 v = *(const f32x4*)(src + (size_t)(k0 + row) * N + n0 + c4);
#pragma unroll
        for (int j = 0; j < 4; ++j) tile[row][c4 + j] = f2bf(v[j]);
    }
    __syncthreads();
    {
        int nn = t >> 3, kc = (t & 7) * 4;
        int n = n0 + nn;
        int r = (MODE == 0) ? n : ((n >> 4) * 32 + (MODE == 2 ? 16 : 0) + (n & 15));
        u16x4 o;
#pragma unroll
        for (int j = 0; j < 4; ++j) o[j] = tile[kc + j][nn];
        *(u16x4*)(dst + (size_t)r * K + k0 + kc) = o;
    }
}

// ---------------- up GEMM (m97 structure) ----------------
// C = A @ B^T where B rows are interleaved {w1,w3} cols.
// Epilogue: h = silu(c1)*c3 [*coef] -> bf16.
template <bool GROUPED>
__global__ __launch_bounds__(256) void up_gemm(
    const unsigned short* __restrict__ xb, const unsigned short* __restrict__ Ball,
    const int* __restrict__ cnt, const int* __restrict__ offs,
    const int* __restrict__ list, const float* __restrict__ cw,
    unsigned short* __restrict__ hout) {
    constexpr int K = DIMD;
    constexpr int LDO = GROUPED ? NI : NSH;
    const int e = GROUPED ? blockIdx.z : 0;
    const int M = GROUPED ? cnt[e] : T_TOK;
    const int rb = blockIdx.y * 128;
    if (rb >= M) return;
    const unsigned short* B = Ball + (GROUPED ? (size_t)e * 2048 * K : 0);
    const int bx = blockIdx.x;
    const int obase = GROUPED ? offs[e] : 0;

    __shared__ unsigned short sA[2][4096];
    __shared__ unsigned short sB[2][4096];

    const int tid = threadIdx.x, lane = tid & 63, wid = tid >> 6;
    const int wm = wid >> 1, wn = wid & 1;

    size_t srcA[2];
    const unsigned short* srcB[2];
    int lbase[2];
#pragma unroll
    for (int L = 0; L < 2; ++L) {
        int chunk = (wid * 2 + L) * 64 + lane;
        int row = chunk >> 2, cc = chunk & 3;
        int gr = rb + row;
        int tok = GROUPED ? list[e * T_TOK + (gr < M ? gr : M - 1)] : gr;
        srcA[L] = (size_t)tok * K + cc * 8;
        srcB[L] = B + (size_t)(bx * 128 + row) * K + cc * 8;
        lbase[L] = (wid * 2 + L) * 512;
    }

    f32x4 acc[4][4];
#pragma unroll
    for (int m = 0; m < 4; ++m)
#pragma unroll
        for (int n = 0; n < 4; ++n) acc[m][n] = (f32x4)0.f;

#pragma unroll
    for (int L = 0; L < 2; ++L) {
        gload16(xb + srcA[L], &sA[0][lbase[L]]);
        gload16(srcB[L], &sB[0][lbase[L]]);
    }
    __syncthreads();
    int cur = 0;
    const int fr = lane & 15, fk = (lane >> 4) * 8;
    for (int t = 0; t < K / 32; ++t) {
        if (t + 1 < K / 32) {
            int k0 = (t + 1) * 32;
#pragma unroll
            for (int L = 0; L < 2; ++L) {
                gload16(xb + srcA[L] + k0, &sA[cur ^ 1][lbase[L]]);
                gload16(srcB[L] + k0, &sB[cur ^ 1][lbase[L]]);
            }
        }
        short8 a[4], b[4];
#pragma unroll
        for (int m = 0; m < 4; ++m)
            a[m] = *(const short8*)&sA[cur][(wm * 64 + m * 16 + fr) * 32 + fk];
#pragma unroll
        for (int n = 0; n < 4; ++n)
            b[n] = *(const short8*)&sB[cur][(wn * 64 + n * 16 + fr) * 32 + fk];
#pragma unroll
        for (int m = 0; m < 4; ++m)
#pragma unroll
            for (int n = 0; n < 4; ++n)
                acc[m][n] = __builtin_amdgcn_mfma_f32_16x16x32_bf16(a[m], b[n], acc[m][n], 0, 0, 0);
        __syncthreads();
        cur ^= 1;
    }

    const int fq = lane >> 4;
#pragma unroll
    for (int m = 0; m < 4; ++m)
#pragma unroll
        for (int n2 = 0; n2 < 2; ++n2)
#pragma unroll
            for (int q = 0; q < 4; ++q) {
                int gr = rb + wm * 64 + m * 16 + fq * 4 + q;
                if (gr < M) {
                    float c1 = acc[m][2 * n2][q], c3 = acc[m][2 * n2 + 1][q];
                    float h = c1 / (1.f + __expf(-c1)) * c3;
                    if (GROUPED) h *= cw[e * T_TOK + gr];
                    int hc = bx * 64 + (wn * 2 + n2) * 16 + fr;
                    hout[(size_t)(obase + gr) * LDO + hc] = f2bf(h);
                }
            }
}

// ---------------- down GEMM (m97 structure) ----------------
template <bool GROUPED>
__global__ __launch_bounds__(256) void down_gemm(
    const unsigned short* __restrict__ Ain, const unsigned short* __restrict__ Ball,
    const int* __restrict__ cnt, const int* __restrict__ offs,
    const int* __restrict__ list, float* __restrict__ out) {
    constexpr int K = GROUPED ? NI : NSH;
    const int e = GROUPED ? blockIdx.z : 0;
    const int M = GROUPED ? cnt[e] : T_TOK;
    const int rb = blockIdx.y * 128;
    if (rb >= M) return;
    const unsigned short* B = Ball + (GROUPED ? (size_t)e * 2048 * K : 0);
    const int bx = blockIdx.x;
    const int obase = GROUPED ? offs[e] : 0;

    __shared__ unsigned short sA[2][4096];
    __shared__ unsigned short sB[2][4096];

    const int tid = threadIdx.x, lane = tid & 63, wid = tid >> 6;
    const int wm = wid >> 1, wn = wid & 1;

    size_t srcA[2];
    const unsigned short* srcB[2];
    int lbase[2];
#pragma unroll
    for (int L = 0; L < 2; ++L) {
        int chunk = (wid * 2 + L) * 64 + lane;
        int row = chunk >> 2, cc = chunk & 3;
        int gr = rb + row;
        int rr = (gr < M) ? gr : (M - 1);
        srcA[L] = (size_t)(obase + rr) * K + cc * 8;
        srcB[L] = B + (size_t)(bx * 128 + row) * K + cc * 8;
        lbase[L] = (wid * 2 + L) * 512;
    }

    f32x4 acc[4][4];
#pragma unroll
    for (int m = 0; m < 4; ++m)
#pragma unroll
        for (int n = 0; n < 4; ++n) acc[m][n] = (f32x4)0.f;

#pragma unroll
    for (int L = 0; L < 2; ++L) {
        gload16(Ain + srcA[L], &sA[0][lbase[L]]);
        gload16(srcB[L], &sB[0][lbase[L]]);
    }
    __syncthreads();
    int cur = 0;
    const int fr = lane & 15, fk = (lane >> 4) * 8;
    for (int t = 0; t < K / 32; ++t) {
        if (t + 1 < K / 32) {
            int k0 = (t + 1) * 32;
#pragma unroll
            for (int L = 0; L < 2; ++L) {
                gload16(Ain + srcA[L] + k0, &sA[cur ^ 1][lbase[L]]);
                gload16(srcB[L] + k0, &sB[cur ^ 1][lbase[L]]);
            }
        }
        short8 a[4], b[4];
#pragma unroll
        for (int m = 0; m < 4; ++m)
            a[m] = *(const short8*)&sA[cur][(wm * 64 + m * 16 + fr) * 32 + fk];
#pragma unroll
        for (int n = 0; n < 4; ++n)
            b[n] = *(const short8*)&sB[cur][(wn * 64 + n * 16 + fr) * 32 + fk];
#pragma unroll
        for (int m = 0; m < 4; ++m)
#pragma unroll
            for (int n = 0; n < 4; ++n)
                acc[m][n] = __builtin_amdgcn_mfma_f32_16x16x32_bf16(a[m], b[n], acc[m][n], 0, 0, 0);
        __syncthreads();
        cur ^= 1;
    }

    const int fq = lane >> 4;
#pragma unroll
    for (int m = 0; m < 4; ++m)
#pragma unroll
        for (int n = 0; n < 4; ++n)
#pragma unroll
            for (int q = 0; q < 4; ++q) {
                int gr = rb + wm * 64 + m * 16 + fq * 4 + q;
                if (gr < M) {
                    int col = bx * 128 + wn * 64 + n * 16 + fr;
                    if (GROUPED) {
                        int tk = list[e * T_TOK + gr];
                        atomicAdd(&out[(size_t)tk * DIMD + col], acc[m][n][q]);
                    } else {
                        out[(size_t)gr * DIMD + col] = acc[m][n][q];
                    }
                }
            }
}

extern "C" void kernel_launch(void* const* d_in, const int* in_sizes, int n_in,
                              void* d_out, int out_size, void* d_ws, size_t ws_size,
                              hipStream_t stream) {
    const float* x   = (const float*)d_in[0];
    const float* gw  = (const float*)d_in[1];
    const float* w1  = (const float*)d_in[2];
    const float* w2  = (const float*)d_in[3];
    const float* w3  = (const float*)d_in[4];
    const float* ws1 = (const float*)d_in[5];
    const float* ws2 = (const float*)d_in[6];
    const float* ws3 = (const float*)d_in[7];
    float* out = (float*)d_out;

    char* p = (char*)d_ws;
    unsigned short* xb   = (unsigned short*)p; p += (size_t)T_TOK * DIMD * 2;        // 16.8 MB
    unsigned short* hs   = (unsigned short*)p; p += (size_t)T_TOK * NSH * 2;         // 16.8 MB
    unsigned short* hbuf = (unsigned short*)p; p += (size_t)T_TOK * TOPK * NI * 2;   // 33.6 MB
    unsigned short* upT  = (unsigned short*)p; p += (size_t)NEXP * 2048 * DIMD * 2;  // 134 MB
    unsigned short* w2T  = (unsigned short*)p; p += (size_t)NEXP * DIMD * NI * 2;    // 67 MB
    unsigned short* upsT = (unsigned short*)p; p += (size_t)2 * NSH * DIMD * 2;      // 16.8 MB
    unsigned short* ws2T = (unsigned short*)p; p += (size_t)DIMD * NSH * 2;          // 8.4 MB
    float* cw = (float*)p;                     p += (size_t)NEXP * T_TOK * 4;
    int* list = (int*)p;                       p += (size_t)NEXP * T_TOK * 4;
    int* cnt = (int*)p;                        p += 256;
    int* offs = (int*)p;                       p += 256;
    if ((size_t)(p - (char*)d_ws) > ws_size) return;  // ws too small -> visible failure

    hipMemsetAsync(cnt, 0, 64, stream);
    gate_kernel<<<T_TOK, 64, 0, stream>>>(x, gw, cnt, list, cw);
    scan_kernel<<<1, 64, 0, stream>>>(cnt, offs);
    cvt_kernel<<<(T_TOK * DIMD / 8) / 256, 256, 0, stream>>>(x, xb);

    // weight pre-pass: bf16 + transpose (+16-col interleave for up weights)
    tq_kernel<1><<<dim3(NI / 32, DIMD / 32, NEXP), 256, 0, stream>>>(w1, upT, DIMD, NI, (size_t)2048 * DIMD);
    tq_kernel<2><<<dim3(NI / 32, DIMD / 32, NEXP), 256, 0, stream>>>(w3, upT, DIMD, NI, (size_t)2048 * DIMD);
    tq_kernel<1><<<dim3(NSH / 32, DIMD / 32, 1), 256, 0, stream>>>(ws1, upsT, DIMD, NSH, 0);
    tq_kernel<2><<<dim3(NSH / 32, DIMD / 32, 1), 256, 0, stream>>>(ws3, upsT, DIMD, NSH, 0);
    tq_kernel<0><<<dim3(DIMD / 32, NI / 32, NEXP), 256, 0, stream>>>(w2, w2T, NI, DIMD, (size_t)DIMD * NI);
    tq_kernel<0><<<dim3(DIMD / 32, NSH / 32, 1), 256, 0, stream>>>(ws2, ws2T, NSH, DIMD, 0);

    // shared expert
    up_gemm<false><<<dim3(2 * NSH / 128, T_TOK / 128, 1), 256, 0, stream>>>(
        xb, upsT, nullptr, nullptr, nullptr, nullptr, hs);
    down_gemm<false><<<dim3(DIMD / 128, T_TOK / 128, 1), 256, 0, stream>>>(
        hs, ws2T, nullptr, nullptr, nullptr, out);
    // routed experts
    up_gemm<true><<<dim3(2 * NI / 128, T_TOK / 128, NEXP), 256, 0, stream>>>(
        xb, upT, cnt, offs, list, cw, hbuf);
    down_gemm<true><<<dim3(DIMD / 128, T_TOK / 128, NEXP), 256, 0, stream>>>(
        hbuf, w2T, cnt, offs, list, out);
}

// Round 3
// 949.561 us; speedup vs baseline: 1.1516x; 1.0742x over previous
//
#include <hip/hip_runtime.h>
#include <hip/hip_bf16.h>
#include <stdint.h>

#define T_TOK 4096
#define DIMD  2048
#define NEXP  16
#define TOPK  4
#define NI    1024
#define NSH   2048

typedef __attribute__((ext_vector_type(8))) short short8;
typedef __attribute__((ext_vector_type(4))) float f32x4;
typedef __attribute__((ext_vector_type(4))) unsigned short u16x4;

__device__ __forceinline__ unsigned short f2bf(float f) {
    union { float f; unsigned u; } v; v.f = f;
    return (unsigned short)((v.u + 0x7fffu + ((v.u >> 16) & 1u)) >> 16);
}

__device__ __forceinline__ void gload16(const void* g, void* l) {
    __builtin_amdgcn_global_load_lds(
        (const __attribute__((address_space(1))) void*)g,
        (__attribute__((address_space(3))) void*)l, 16, 0, 0);
}

// ---------------- gate + routing ----------------
__global__ __launch_bounds__(64) void gate_kernel(const float* __restrict__ x,
                                                  const float* __restrict__ gw,
                                                  int* __restrict__ cnt,
                                                  int* __restrict__ list,
                                                  float* __restrict__ cw) {
    int t = blockIdx.x;
    int lane = threadIdx.x;
    float acc[NEXP];
#pragma unroll
    for (int e = 0; e < NEXP; ++e) acc[e] = 0.f;
    const float* xr = x + (size_t)t * DIMD;
    for (int d0 = 0; d0 < DIMD; d0 += 64) {
        int d = d0 + lane;
        float xv = xr[d];
        const f32x4* g = (const f32x4*)(gw + (size_t)d * NEXP);
#pragma unroll
        for (int q = 0; q < 4; ++q) {
            f32x4 gv = g[q];
#pragma unroll
            for (int j = 0; j < 4; ++j) acc[q * 4 + j] += xv * gv[j];
        }
    }
#pragma unroll
    for (int e = 0; e < NEXP; ++e) {
        float v = acc[e];
#pragma unroll
        for (int off = 32; off; off >>= 1) v += __shfl_xor(v, off, 64);
        acc[e] = v;
    }
    float m = acc[0];
#pragma unroll
    for (int e = 1; e < NEXP; ++e) m = fmaxf(m, acc[e]);
    float s = 0.f;
#pragma unroll
    for (int e = 0; e < NEXP; ++e) { acc[e] = expf(acc[e] - m); s += acc[e]; }
    float inv = 1.f / s;
#pragma unroll
    for (int e = 0; e < NEXP; ++e) acc[e] *= inv;

    if (lane == 0) {
        bool used[NEXP];
#pragma unroll
        for (int e = 0; e < NEXP; ++e) used[e] = false;
        for (int k = 0; k < TOPK; ++k) {
            int be = 0; float bv = -1.f;
            for (int e = 0; e < NEXP; ++e)
                if (!used[e] && acc[e] > bv) { bv = acc[e]; be = e; }
            used[be] = true;
            int r = atomicAdd(&cnt[be], 1);
            list[be * T_TOK + r] = t;
            cw[be * T_TOK + r] = bv;
        }
    }
}

__global__ void scan_kernel(const int* __restrict__ cnt, int* __restrict__ offs) {
    if (threadIdx.x == 0) {
        int o = 0;
        for (int e = 0; e < NEXP; ++e) { offs[e] = o; o += cnt[e]; }
        offs[NEXP] = o;
    }
}

// ---------------- x fp32 -> bf16 ----------------
__global__ __launch_bounds__(256) void cvt_kernel(const float* __restrict__ x,
                                                  unsigned short* __restrict__ xb) {
    int i = blockIdx.x * 256 + threadIdx.x;
    const f32x4* src = (const f32x4*)x;
    f32x4 a = src[i * 2 + 0];
    f32x4 b = src[i * 2 + 1];
    short8 o;
#pragma unroll
    for (int j = 0; j < 4; ++j) o[j] = (short)f2bf(a[j]);
#pragma unroll
    for (int j = 0; j < 4; ++j) o[4 + j] = (short)f2bf(b[j]);
    ((short8*)xb)[i] = o;
}

// ---------------- weight transpose + convert ----------------
// src fp32 [K][N] -> dst bf16 [N'][K].
// MODE 0: r = n. MODE 1: r = (n>>4)*32 + (n&15). MODE 2: +16.
template <int MODE>
__global__ __launch_bounds__(256) void tq_kernel(const float* __restrict__ src,
                                                 unsigned short* __restrict__ dst,
                                                 int K, int N, size_t dstStrideE) {
    int e = blockIdx.z;
    src += (size_t)e * K * N;
    dst += (size_t)e * dstStrideE;
    __shared__ unsigned short tile[32][36];
    int t = threadIdx.x;
    int k0 = blockIdx.y * 32, n0 = blockIdx.x * 32;
    {
        int row = t >> 3, c4 = (t & 7) * 4;
        f32x4 v = *(const f32x4*)(src + (size_t)(k0 + row) * N + n0 + c4);
#pragma unroll
        for (int j = 0; j < 4; ++j) tile[row][c4 + j] = f2bf(v[j]);
    }
    __syncthreads();
    {
        int nn = t >> 3, kc = (t & 7) * 4;
        int n = n0 + nn;
        int r = (MODE == 0) ? n : ((n >> 4) * 32 + (MODE == 2 ? 16 : 0) + (n & 15));
        u16x4 o;
#pragma unroll
        for (int j = 0; j < 4; ++j) o[j] = tile[kc + j][nn];
        *(u16x4*)(dst + (size_t)r * K + k0 + kc) = o;
    }
}

// ================= 256x256 8-phase GEMM =================
// KIND: 0 shared-up, 1 routed-up, 2 shared-down(split-K), 3 routed-down
// A bf16 [M][ASTRIDE] (row-gathered for routed), B bf16 [N][BSTRIDE] (B^T rows).
// LDS layout (dyn 128KB): d*65536 + {A:0, B:32768} + row*128 + swz-slot*16.

#define STA(u, d, kt) do { \
    gload16(gA[u][0] + (kt) * 64, (void*)(smem + (d) * 65536 + ldsA[u][0])); \
    gload16(gA[u][1] + (kt) * 64, (void*)(smem + (d) * 65536 + ldsA[u][1])); \
  } while (0)
#define STB(u, d, kt) do { \
    gload16(gB[u][0] + (kt) * 64, (void*)(smem + (d) * 65536 + 32768 + ldsB[u][0])); \
    gload16(gB[u][1] + (kt) * 64, (void*)(smem + (d) * 65536 + 32768 + ldsB[u][1])); \
  } while (0)
#define VMC4 asm volatile("s_waitcnt vmcnt(4)" ::: "memory")

#define PHASE(MH, NH, D, STAGES, VMW) do { \
    short8 aF[4][2], bF[2][2]; \
    _Pragma("unroll") \
    for (int m2 = 0; m2 < 4; ++m2) { \
      int row = wm * 128 + ((MH) * 4 + m2) * 16 + fr; \
      const char* bp = smem + (D) * 65536 + row * 128; \
      aF[m2][0] = *(const short8*)(bp + kA0); \
      aF[m2][1] = *(const short8*)(bp + kA1); \
    } \
    _Pragma("unroll") \
    for (int n2 = 0; n2 < 2; ++n2) { \
      int row = wn * 64 + ((NH) * 2 + n2) * 16 + fr; \
      const char* bp = smem + (D) * 65536 + 32768 + row * 128; \
      bF[n2][0] = *(const short8*)(bp + kA0); \
      bF[n2][1] = *(const short8*)(bp + kA1); \
    } \
    STAGES; \
    VMW; \
    __builtin_amdgcn_s_barrier(); \
    asm volatile("s_waitcnt lgkmcnt(0)" ::: "memory"); \
    __builtin_amdgcn_sched_barrier(0); \
    __builtin_amdgcn_s_setprio(1); \
    _Pragma("unroll") \
    for (int m2 = 0; m2 < 4; ++m2) { \
      _Pragma("unroll") \
      for (int n2 = 0; n2 < 2; ++n2) { \
        acc[(MH) * 4 + m2][(NH) * 2 + n2] = __builtin_amdgcn_mfma_f32_16x16x32_bf16( \
            aF[m2][0], bF[n2][0], acc[(MH) * 4 + m2][(NH) * 2 + n2], 0, 0, 0); \
        acc[(MH) * 4 + m2][(NH) * 2 + n2] = __builtin_amdgcn_mfma_f32_16x16x32_bf16( \
            aF[m2][1], bF[n2][1], acc[(MH) * 4 + m2][(NH) * 2 + n2], 0, 0, 0); \
      } \
    } \
    __builtin_amdgcn_s_setprio(0); \
    __builtin_amdgcn_s_barrier(); \
  } while (0)

template <int KIND>
__global__ __launch_bounds__(512, 2) void gemm8p(
    const unsigned short* __restrict__ A, const unsigned short* __restrict__ Ball,
    const int* __restrict__ cnt, const int* __restrict__ offs,
    const int* __restrict__ list, const float* __restrict__ cw,
    unsigned short* __restrict__ hout, float* __restrict__ fout) {
    constexpr bool ROUTED = (KIND == 1 || KIND == 3);
    constexpr bool UP = (KIND <= 1);
    constexpr int K = (KIND <= 1) ? 2048 : 1024;      // per-pass K
    constexpr int NITER = K / 128;
    constexpr int ASTR = (KIND == 3) ? 1024 : 2048;
    constexpr int BSTR = (KIND == 3) ? 1024 : 2048;

    const int bx = blockIdx.x, by = blockIdx.y;
    const int e = ROUTED ? blockIdx.z : 0;
    const int M = ROUTED ? cnt[e] : T_TOK;
    const int rb = by * 256;
    if (ROUTED && rb >= M) return;
    const int obase = ROUTED ? offs[e] : 0;
    const int kb = (KIND == 2) ? blockIdx.z * 1024 : 0;
    const unsigned short* Bp = Ball +
        (KIND == 1 ? (size_t)e * 2048 * 2048 : KIND == 3 ? (size_t)e * 2048 * 1024 : 0);

    extern __shared__ char smem[];

    const int tid = threadIdx.x;
    const int lane = tid & 63, wid = tid >> 6;
    const int wm = wid >> 2, wn = wid & 3;
    const int fr = lane & 15, fq = lane >> 4;
    const int swz = (fr & 7) << 4;
    const int kA0 = (fq * 16) ^ swz;
    const int kA1 = (64 + fq * 16) ^ swz;

    // stage maps: units u=0,1, issues i=0,1 (chunk c = tid + 512*i)
    int ldsA[2][2], ldsB[2][2];
    const unsigned short* gA[2][2];
    const unsigned short* gB[2][2];
#pragma unroll
    for (int u = 0; u < 2; ++u)
#pragma unroll
        for (int i = 0; i < 2; ++i) {
            int rowA = i * 128 + u * 64 + (tid >> 3);
            int kcA = (tid & 7) ^ (rowA & 7);
            ldsA[u][i] = i * 16384 + u * 8192 + tid * 16;
            int gr = rb + rowA;
            int cr = (gr < M) ? gr : (M - 1);
            size_t arow;
            if (KIND == 1)      arow = (size_t)list[e * T_TOK + cr];
            else if (KIND == 3) arow = (size_t)(obase + cr);
            else                arow = (size_t)gr;   // dense: gr < 4096 always
            gA[u][i] = A + arow * ASTR + kb + kcA * 8;

            int s = (tid >> 8) + 2 * i;
            int rowB = s * 64 + u * 32 + ((tid >> 3) & 31);
            int kcB = (tid & 7) ^ (rowB & 7);
            ldsB[u][i] = s * 8192 + u * 4096 + (tid & 255) * 16;
            gB[u][i] = Bp + (size_t)(bx * 256 + rowB) * BSTR + kb + kcB * 8;
        }

    f32x4 acc[8][4];
#pragma unroll
    for (int m = 0; m < 8; ++m)
#pragma unroll
        for (int n = 0; n < 4; ++n) acc[m][n] = (f32x4)0.f;

    // prologue: kt0 -> d0 (all units); kt1 -> d1 (SA0, SB0)
    STA(0, 0, 0); STA(1, 0, 0); STB(0, 0, 0); STB(1, 0, 0);
    STA(0, 1, 1); STB(0, 1, 1);
    asm volatile("s_waitcnt vmcnt(4)" ::: "memory");
    __builtin_amdgcn_s_barrier();

    for (int it = 0; it < NITER; ++it) {
        const bool more = (it + 1 < NITER);
        const int ktb = 2 * it + 1, ktc = 2 * it + 2, ktd = 2 * it + 3;
        PHASE(0, 0, 0, { STA(1, 1, ktb); }, );
        PHASE(0, 1, 0, { STB(1, 1, ktb); }, );
        PHASE(1, 0, 0, { if (more) STA(0, 0, ktc); }, );
        PHASE(1, 1, 0, { if (more) STB(0, 0, ktc); }, VMC4);
        PHASE(0, 0, 1, { if (more) STA(1, 0, ktc); }, );
        PHASE(0, 1, 1, { if (more) STB(1, 0, ktc); }, );
        PHASE(1, 0, 1, { if (more) STA(0, 1, ktd); }, );
        PHASE(1, 1, 1, { if (more) STB(0, 1, ktd); }, VMC4);
    }

    // epilogue
    if constexpr (UP) {
        constexpr int LDO = (KIND == 1) ? NI : NSH;
#pragma unroll
        for (int mf = 0; mf < 8; ++mf)
#pragma unroll
            for (int q = 0; q < 4; ++q) {
                int gr = rb + wm * 128 + mf * 16 + fq * 4 + q;
                if (gr < M) {
                    float coef = 1.f;
                    if constexpr (KIND == 1) coef = cw[e * T_TOK + gr];
                    size_t orow = (size_t)(obase + gr) * LDO;
#pragma unroll
                    for (int nfp = 0; nfp < 2; ++nfp) {
                        float c1 = acc[mf][2 * nfp][q], c3 = acc[mf][2 * nfp + 1][q];
                        float h = c1 / (1.f + __expf(-c1)) * c3 * coef;
                        int ncol = (bx * 8 + wn * 2 + nfp) * 16 + fr;
                        hout[orow + ncol] = f2bf(h);
                    }
                }
            }
    } else {
#pragma unroll
        for (int mf = 0; mf < 8; ++mf)
#pragma unroll
            for (int q = 0; q < 4; ++q) {
                int gr = rb + wm * 128 + mf * 16 + fq * 4 + q;
                if (gr < M) {
                    int orow = (KIND == 3) ? list[e * T_TOK + gr] : gr;
#pragma unroll
                    for (int nf = 0; nf < 4; ++nf) {
                        int col = bx * 256 + wn * 64 + nf * 16 + fr;
                        atomicAdd(fout + (size_t)orow * DIMD + col, acc[mf][nf][q]);
                    }
                }
            }
    }
}

extern "C" void kernel_launch(void* const* d_in, const int* in_sizes, int n_in,
                              void* d_out, int out_size, void* d_ws, size_t ws_size,
                              hipStream_t stream) {
    const float* x   = (const float*)d_in[0];
    const float* gw  = (const float*)d_in[1];
    const float* w1  = (const float*)d_in[2];
    const float* w2  = (const float*)d_in[3];
    const float* w3  = (const float*)d_in[4];
    const float* ws1 = (const float*)d_in[5];
    const float* ws2 = (const float*)d_in[6];
    const float* ws3 = (const float*)d_in[7];
    float* out = (float*)d_out;

    char* p = (char*)d_ws;
    unsigned short* xb   = (unsigned short*)p; p += (size_t)T_TOK * DIMD * 2;
    unsigned short* hs   = (unsigned short*)p; p += (size_t)T_TOK * NSH * 2;
    unsigned short* hbuf = (unsigned short*)p; p += (size_t)T_TOK * TOPK * NI * 2;
    unsigned short* upT  = (unsigned short*)p; p += (size_t)NEXP * 2048 * DIMD * 2;
    unsigned short* w2T  = (unsigned short*)p; p += (size_t)NEXP * DIMD * NI * 2;
    unsigned short* upsT = (unsigned short*)p; p += (size_t)2 * NSH * DIMD * 2;
    unsigned short* ws2T = (unsigned short*)p; p += (size_t)DIMD * NSH * 2;
    float* cw = (float*)p;                     p += (size_t)NEXP * T_TOK * 4;
    int* list = (int*)p;                       p += (size_t)NEXP * T_TOK * 4;
    int* cnt = (int*)p;                        p += 256;
    int* offs = (int*)p;                       p += 256;
    if ((size_t)(p - (char*)d_ws) > ws_size) return;

    hipFuncSetAttribute((const void*)&gemm8p<0>, hipFuncAttributeMaxDynamicSharedMemorySize, 131072);
    hipFuncSetAttribute((const void*)&gemm8p<1>, hipFuncAttributeMaxDynamicSharedMemorySize, 131072);
    hipFuncSetAttribute((const void*)&gemm8p<2>, hipFuncAttributeMaxDynamicSharedMemorySize, 131072);
    hipFuncSetAttribute((const void*)&gemm8p<3>, hipFuncAttributeMaxDynamicSharedMemorySize, 131072);

    hipMemsetAsync(cnt, 0, 64, stream);
    hipMemsetAsync(out, 0, (size_t)out_size * 4, stream);
    gate_kernel<<<T_TOK, 64, 0, stream>>>(x, gw, cnt, list, cw);
    scan_kernel<<<1, 64, 0, stream>>>(cnt, offs);
    cvt_kernel<<<(T_TOK * DIMD / 8) / 256, 256, 0, stream>>>(x, xb);

    tq_kernel<1><<<dim3(NI / 32, DIMD / 32, NEXP), 256, 0, stream>>>(w1, upT, DIMD, NI, (size_t)2048 * DIMD);
    tq_kernel<2><<<dim3(NI / 32, DIMD / 32, NEXP), 256, 0, stream>>>(w3, upT, DIMD, NI, (size_t)2048 * DIMD);
    tq_kernel<1><<<dim3(NSH / 32, DIMD / 32, 1), 256, 0, stream>>>(ws1, upsT, DIMD, NSH, 0);
    tq_kernel<2><<<dim3(NSH / 32, DIMD / 32, 1), 256, 0, stream>>>(ws3, upsT, DIMD, NSH, 0);
    tq_kernel<0><<<dim3(DIMD / 32, NI / 32, NEXP), 256, 0, stream>>>(w2, w2T, NI, DIMD, (size_t)DIMD * NI);
    tq_kernel<0><<<dim3(DIMD / 32, NSH / 32, 1), 256, 0, stream>>>(ws2, ws2T, NSH, DIMD, 0);

    // shared expert: up (N=4096 interleaved), down (split-K=2, atomic into zeroed out)
    gemm8p<0><<<dim3(16, 16, 1), 512, 131072, stream>>>(
        xb, upsT, nullptr, nullptr, nullptr, nullptr, hs, nullptr);
    gemm8p<2><<<dim3(8, 16, 2), 512, 131072, stream>>>(
        hs, ws2T, nullptr, nullptr, nullptr, nullptr, nullptr, out);
    // routed experts
    gemm8p<1><<<dim3(8, 16, NEXP), 512, 131072, stream>>>(
        xb, upT, cnt, offs, list, cw, hbuf, nullptr);
    gemm8p<3><<<dim3(8, 16, NEXP), 512, 131072, stream>>>(
        hbuf, w2T, cnt, offs, list, nullptr, nullptr, out);
}